// Round 6
// baseline (1319.757 us; speedup 1.0000x reference)
//
#include <hip/hip_runtime.h>

#define Bsz 4096
#define Fsz 32
#define Dsz 64
#define Psz 496
#define RPW 64      // rows per wave
#define WPB 4       // waves per block (256 threads)
#define RB  8       // rows sharing one w-chunk reload
#define DC  8       // d-chunk size (w values held in VGPRs at a time)

// Rounds 3-5 post-mortem: three variants (compiler remat / asm pin / raw asm
// loads) all hit 341 us, VALUBusy 69%, VGPR=36 -- the SIMD ISSUE PORT is
// saturated ~50/50 by fmacs and per-row w-reloads (global or scratch, same
// issue cost). The allocator refuses to keep 64 invariant floats in VGPRs.
// This version stops fighting it: w-chunks of 8 are reloaded from LDS but
// AMORTIZED over RB=8 rows (acc[8] live), cutting reloads/row from 64 to 8.
//   issue/row ~ 128 (fmac) + 8 (ds_read) + 8 (s_load share) + misc ~ 156 cyc
// LDS reads sW[d][lane]: consecutive lanes -> consecutive banks, 2-way
// wave64 aliasing only (free). No transpose, no padding needed.
// Accumulation: d ascending per row (dc outer, k inner), single fmaf chain,
// then one vj multiply -> bitwise identical to the absmax==0.0 kernels.
__global__ __launch_bounds__(256, 8)   // VGPR cap 64, target 8 waves/SIMD
void bilinear_sblk_kernel(const float* __restrict__ in,
                          const float* __restrict__ W,
                          float* __restrict__ out)
{
    __shared__ float sW[Dsz][Dsz];   // [d][e], 16 KB

    const int p    = blockIdx.x;
    const int tid  = threadIdx.x;
    const int lane = tid & 63;

    // Wave-uniform base row in an SGPR so vi loads scalarize (s_load).
    const int bb0 = __builtin_amdgcn_readfirstlane(
                        blockIdx.y * (RPW * WPB) + (tid >> 6) * RPW);

    // Decode pair p -> (i, j), matching np.triu_indices(F, k=1) order.
    int i = 0, rem = p;
    while (rem >= Fsz - 1 - i) { rem -= Fsz - 1 - i; ++i; }
    const int j = i + 1 + rem;

    // ---- Stage W[p] (64x64 fp32) into LDS: 256 threads x 4 float4 ----
    {
        const float4* gW  = (const float4*)(W + (size_t)p * Dsz * Dsz);
        float4*       sWv = (float4*)(&sW[0][0]);
#pragma unroll
        for (int k = 0; k < 4; ++k) sWv[tid + k * 256] = gW[tid + k * 256];
    }
    __syncthreads();

    const float* vib = in  + ((size_t)bb0 * Fsz + i) * Dsz;          // uniform
    const float* vjb = in  + ((size_t)bb0 * Fsz + j) * Dsz + lane;   // per-lane
    float*       opb = out + ((size_t)bb0 * Psz + p) * Dsz + lane;   // per-lane

#pragma unroll 1
    for (int rb = 0; rb < RPW / RB; ++rb) {
        float acc[RB];
#pragma unroll
        for (int r = 0; r < RB; ++r) acc[r] = 0.0f;

#pragma unroll
        for (int dc = 0; dc < Dsz / DC; ++dc) {
            // 8 w values for this lane's e-column, shared by 8 rows.
            float wv[DC];
#pragma unroll
            for (int k = 0; k < DC; ++k) wv[k] = sW[dc * DC + k][lane];

#pragma unroll
            for (int r = 0; r < RB; ++r) {
                const size_t row_off = (size_t)(rb * RB + r) * (Fsz * Dsz);
#pragma unroll
                for (int k = 0; k < DC; ++k)
                    acc[r] = fmaf(vib[row_off + dc * DC + k], wv[k], acc[r]);
            }
        }

#pragma unroll
        for (int r = 0; r < RB; ++r) {
            const size_t ro = (size_t)(rb * RB + r);
            // 256 B contiguous per wave-instruction; nontemporal keeps the
            // 520 MB output stream from evicting 'in'/W in L2/L3.
            __builtin_nontemporal_store(acc[r] * vjb[ro * (Fsz * Dsz)],
                                        opb + ro * ((size_t)Psz * Dsz));
        }
    }
}

extern "C" void kernel_launch(void* const* d_in, const int* in_sizes, int n_in,
                              void* d_out, int out_size, void* d_ws, size_t ws_size,
                              hipStream_t stream) {
    const float* in  = (const float*)d_in[0];
    const float* W   = (const float*)d_in[1];
    float*       out = (float*)d_out;

    dim3 grid(Psz, Bsz / (RPW * WPB));   // (496, 16)
    bilinear_sblk_kernel<<<grid, 256, 0, stream>>>(in, W, out);
}